// Round 12
// baseline (51.832 us; speedup 1.0000x reference)
//
#include <hip/hip_runtime.h>
#include <math.h>

#define LL 1024
#define DD 512
#define HH 256

// ws layout (floats):
//   pC : [4][512][1024] @ 0         gemm K-partials (n = mat*256+h)   (8 MB)
//   pz : [2][1024][1024] @ 2097152  pairwise h-half partials          (8 MB)

// ---------------------------------------------------------------------------
// Kernel 1 (R7/R10/R11-proven): GEMM partials. Tile 128i x 64n x 128k,
// 512 thr, 4i x 4n per thread, grid (8,8,4)=256. Dbuf BK=32.
// ---------------------------------------------------------------------------
__global__ __launch_bounds__(512) void sp_gemm(
    const float* __restrict__ S, const float* __restrict__ W1,
    float* __restrict__ pC) {
  __shared__ float Sl[2][128][36];   // 36.9 KB
  __shared__ float Wl[2][64][36];    // 18.4 KB

  const int tid = threadIdx.x;
  const int tx  = tid & 15;          // n = n0 + tx + 16b
  const int ty  = tid >> 4;          // i = i0 + 4ty + a, ty 0..31
  const int i0  = blockIdx.x * 128;
  const int n0  = blockIdx.y * 64;
  const int kz  = blockIdx.z * 128;

  const int srow = tid >> 3;         // 0..63
  const int ssl  = tid & 7;
  const int wn   = n0 + srow;
  const float* s0 = S + (size_t)(i0 + srow) * DD + kz + 4 * ssl;
  const float* s1 = S + (size_t)(i0 + 64 + srow) * DD + kz + 4 * ssl;
  const float* w0 = W1 + (size_t)(wn & 255) * (2 * DD) + (wn >> 8) * DD + kz + 4 * ssl;

  float4 sA, sB, wA;
  auto ld = [&](int c) {
    sA = *(const float4*)(s0 + 32 * c);
    sB = *(const float4*)(s1 + 32 * c);
    wA = *(const float4*)(w0 + 32 * c);
  };
  auto st = [&](int b) {
    *(float4*)&Sl[b][srow][4 * ssl]      = sA;
    *(float4*)&Sl[b][64 + srow][4 * ssl] = sB;
    *(float4*)&Wl[b][srow][4 * ssl]      = wA;
  };

  float acc[4][4] = {{0.f}};

  ld(0); st(0); __syncthreads();

  for (int c = 0; c < 4; ++c) {
    const int cur = c & 1;
    if (c < 3) ld(c + 1);
    #pragma unroll 2
    for (int k4 = 0; k4 < 8; ++k4) {
      float4 wf[4], sf[4];
      #pragma unroll
      for (int b = 0; b < 4; ++b) wf[b] = *(const float4*)&Wl[cur][tx + 16 * b][4 * k4];
      #pragma unroll
      for (int a = 0; a < 4; ++a) sf[a] = *(const float4*)&Sl[cur][4 * ty + a][4 * k4];
      #pragma unroll
      for (int a = 0; a < 4; ++a) {
        #pragma unroll
        for (int b = 0; b < 4; ++b) {
          acc[a][b] += sf[a].x * wf[b].x + sf[a].y * wf[b].y +
                       sf[a].z * wf[b].z + sf[a].w * wf[b].w;
        }
      }
    }
    if (c < 3) st(cur ^ 1);
    __syncthreads();
  }

  float* base = pC + (size_t)blockIdx.z * (512 * LL);
  #pragma unroll
  for (int b = 0; b < 4; ++b) {
    const int n = n0 + tx + 16 * b;
    *(float4*)(base + (size_t)n * LL + i0 + 4 * ty) =
        make_float4(acc[0][b], acc[1][b], acc[2][b], acc[3][b]);
  }
}

// ---------------------------------------------------------------------------
// Kernel 2: pairwise, h-split 2, 4i x 4j per thread (VALU:LDS = 32:32,
// the balance point; R11's 2x4 was 16:24 LDS-pipe-bound).
// Block z covers h in [128z, 128z+128):
//   pz[z](i,j) = A_z(i) + B_z(j) + sum_h |t_i+u_j| * w2_h
// 256 thr, tile 64x64, panels 74 KB -> 2 blocks/CU = 8 waves/CU = 2/SIMD.
// Staging sums the 4 gemm K-partials and folds b1 into T.
// Banks: T-read 4 addrs x 16-lane broadcast (free); U-read 2-way (free).
// ---------------------------------------------------------------------------
__global__ __launch_bounds__(256) void sp_pairwise(
    const float* __restrict__ pC, const float* __restrict__ b1,
    const float* __restrict__ W2, float* __restrict__ pz) {
  __shared__ float Tl[128][72];   // 36.9 KB
  __shared__ float Ul[128][72];   // 36.9 KB
  __shared__ float PR[2][128];
  __shared__ float As[64], Bs[64];

  const int tid = threadIdx.x;
  const int tx  = tid & 15;       // j = j0 + 4tx + b
  const int ty  = tid >> 4;       // i = i0 + 4ty + a, ty 0..15
  const int j0  = blockIdx.x * 64;
  const int i0  = blockIdx.y * 64;
  const int hz  = blockIdx.z * 128;
  const size_t PZ = 512 * (size_t)LL;

  // stage: panel element = sum of 4 K-partials (+ b1 for T)
  #pragma unroll 2
  for (int q = 0; q < 8; ++q) {
    const int m = q * 256 + tid;           // 0..2047
    const int hh = m >> 4;                 // 0..127
    const int g4 = (m & 15) * 4;
    const int h  = hz + hh;
    const float* pt = pC + (size_t)h * LL + i0 + g4;
    const float* pu = pC + (size_t)(HH + h) * LL + j0 + g4;
    const float4 t0 = *(const float4*)(pt);
    const float4 t1 = *(const float4*)(pt + PZ);
    const float4 t2 = *(const float4*)(pt + 2 * PZ);
    const float4 t3 = *(const float4*)(pt + 3 * PZ);
    const float4 u0 = *(const float4*)(pu);
    const float4 u1 = *(const float4*)(pu + PZ);
    const float4 u2 = *(const float4*)(pu + 2 * PZ);
    const float4 u3 = *(const float4*)(pu + 3 * PZ);
    const float bb = b1[h];
    *(float4*)&Tl[hh][g4] = make_float4(t0.x + t1.x + t2.x + t3.x + bb,
                                        t0.y + t1.y + t2.y + t3.y + bb,
                                        t0.z + t1.z + t2.z + t3.z + bb,
                                        t0.w + t1.w + t2.w + t3.w + bb);
    *(float4*)&Ul[hh][g4] = make_float4(u0.x + u1.x + u2.x + u3.x,
                                        u0.y + u1.y + u2.y + u3.y,
                                        u0.z + u1.z + u2.z + u3.z,
                                        u0.w + u1.w + u2.w + u3.w);
  }
  __syncthreads();

  // rank-1 prologue over this h-half: 128 cols x 2 h-slices of 64
  {
    const int x = tid & 127, hs = tid >> 7;    // hs 0..1
    const float* pan = (x < 64) ? &Tl[0][x] : &Ul[0][x - 64];
    float p = 0.f;
    #pragma unroll 8
    for (int n = 0; n < 64; ++n) {
      const int hh = hs * 64 + n;
      p = fmaf(pan[hh * 72], W2[hz + hh], p);
    }
    PR[hs][x] = p;
  }
  __syncthreads();
  if (tid < 128) {
    const float s = PR[0][tid] + PR[1][tid];
    if (tid < 64) As[tid] = s; else Bs[tid - 64] = s;
  }
  __syncthreads();

  float acc[4][4] = {{0.f}};

  #pragma unroll 4
  for (int hh = 0; hh < 128; ++hh) {
    const float4 tv4 = *(const float4*)&Tl[hh][4 * ty];
    const float4 uv4 = *(const float4*)&Ul[hh][4 * tx];
    const float w = W2[hz + hh];
    const float tv[4] = {tv4.x, tv4.y, tv4.z, tv4.w};
    const float uv[4] = {uv4.x, uv4.y, uv4.z, uv4.w};
    #pragma unroll
    for (int a = 0; a < 4; ++a) {
      #pragma unroll
      for (int b = 0; b < 4; ++b) {
        acc[a][b] = fmaf(fabsf(tv[a] + uv[b]), w, acc[a][b]);
      }
    }
  }

  float* po = pz + (size_t)blockIdx.z * ((size_t)LL * LL);
  #pragma unroll
  for (int a = 0; a < 4; ++a) {
    const float Ai = As[4 * ty + a];
    float4 v;
    v.x = acc[a][0] + Ai + Bs[4 * tx + 0];
    v.y = acc[a][1] + Ai + Bs[4 * tx + 1];
    v.z = acc[a][2] + Ai + Bs[4 * tx + 2];
    v.w = acc[a][3] + Ai + Bs[4 * tx + 3];
    *(float4*)(po + (size_t)(i0 + 4 * ty + a) * LL + j0 + 4 * tx) = v;
  }
}

// ---------------------------------------------------------------------------
// Kernel 3: out = sigmoid(0.25*(Q + Q^T) + b2), Q = pz0+pz1.
// Triangular grid: block (bx,by) with by<=bx computes the symmetrized
// 64x64 tile once and writes it to BOTH (i,j) and (j,i) positions
// (halves pz reads: 16 MB -> 8 MB). by>bx blocks exit immediately.
// ---------------------------------------------------------------------------
__global__ __launch_bounds__(1024) void sp_symsig(
    const float* __restrict__ pz, const float* __restrict__ b2,
    float* __restrict__ out) {
  const int bx = blockIdx.x, by = blockIdx.y;
  if (by > bx) return;
  __shared__ float B[64][65];
  __shared__ float O2[64][65];
  const int i0 = by * 64;
  const int j0 = bx * 64;
  const int r  = threadIdx.x >> 4;   // 0..63
  const int g  = threadIdx.x & 15;   // 0..15
  const size_t L2 = (size_t)LL * LL;

  // mirror tile: Q(j0+r, i0+col), summed over the 2 h-halves
  const float* pm = pz + (size_t)(j0 + r) * LL + i0 + 4 * g;
  const float4 m0 = *(const float4*)(pm);
  const float4 m1 = *(const float4*)(pm + L2);
  B[r][4 * g + 0] = m0.x + m1.x;
  B[r][4 * g + 1] = m0.y + m1.y;
  B[r][4 * g + 2] = m0.z + m1.z;
  B[r][4 * g + 3] = m0.w + m1.w;
  __syncthreads();

  const float* pd = pz + (size_t)(i0 + r) * LL + j0 + 4 * g;
  const float4 d0 = *(const float4*)(pd);
  const float4 d1 = *(const float4*)(pd + L2);
  const float bb = b2[0];
  float4 o;
  float x;
  x = 0.25f * (d0.x + d1.x + B[4 * g + 0][r]) + bb; o.x = 1.f / (1.f + expf(-x));
  x = 0.25f * (d0.y + d1.y + B[4 * g + 1][r]) + bb; o.y = 1.f / (1.f + expf(-x));
  x = 0.25f * (d0.z + d1.z + B[4 * g + 2][r]) + bb; o.z = 1.f / (1.f + expf(-x));
  x = 0.25f * (d0.w + d1.w + B[4 * g + 3][r]) + bb; o.w = 1.f / (1.f + expf(-x));
  *(float4*)(out + (size_t)(i0 + r) * LL + j0 + 4 * g) = o;

  if (bx == by) return;   // diagonal tile is already symmetric

  // write the transposed tile to (j0.., i0..) via LDS transpose
  O2[r][4 * g + 0] = o.x;
  O2[r][4 * g + 1] = o.y;
  O2[r][4 * g + 2] = o.z;
  O2[r][4 * g + 3] = o.w;
  __syncthreads();
  float4 t;
  t.x = O2[4 * g + 0][r];
  t.y = O2[4 * g + 1][r];
  t.z = O2[4 * g + 2][r];
  t.w = O2[4 * g + 3][r];
  *(float4*)(out + (size_t)(j0 + r) * LL + i0 + 4 * g) = t;
}

// ---------------------------------------------------------------------------
extern "C" void kernel_launch(void* const* d_in, const int* in_sizes, int n_in,
                              void* d_out, int out_size, void* d_ws, size_t ws_size,
                              hipStream_t stream) {
  const float* S  = (const float*)d_in[0];   // [L, D]
  const float* W1 = (const float*)d_in[1];   // [H, 2D]
  const float* b1 = (const float*)d_in[2];   // [H]
  const float* W2 = (const float*)d_in[3];   // [1, H]
  const float* b2 = (const float*)d_in[4];   // [1]
  float* out = (float*)d_out;

  float* ws = (float*)d_ws;
  float* pC = ws;                      // [4][512][1024]
  float* pz = ws + 4 * 512 * LL;       // [2][1024][1024]

  hipLaunchKernelGGL(sp_gemm, dim3(8, 8, 4), dim3(512), 0, stream,
                     S, W1, pC);
  hipLaunchKernelGGL(sp_pairwise, dim3(16, 16, 2), dim3(256), 0, stream,
                     pC, b1, W2, pz);
  hipLaunchKernelGGL(sp_symsig, dim3(16, 16), dim3(1024), 0, stream,
                     pz, b2, out);
}

// Round 13
// 51.744 us; speedup vs baseline: 1.0017x; 1.0017x over previous
//
#include <hip/hip_runtime.h>
#include <hip/hip_bf16.h>
#include <math.h>

#define LL 1024
#define DD 512
#define HH 256

// ws layout:
//   O  : [512][1024] bf16 (ushort) @ 0      rows 0:256 = t(+b1), 256:512 = u  (1 MB)
//   pz : [2][1024][1024] f32 @ 262144 f     pairwise h-half partials          (8 MB)

__device__ __forceinline__ ushort f2bf(float f) {
  __hip_bfloat16 h = __float2bfloat16(f);
  return *reinterpret_cast<ushort*>(&h);
}
__device__ __forceinline__ float bf_lo(unsigned int u) {
  return __uint_as_float(u << 16);
}
__device__ __forceinline__ float bf_hi(unsigned int u) {
  return __uint_as_float(u & 0xffff0000u);
}

// ---------------------------------------------------------------------------
// Kernel 1 (R8-proven shape): full-K GEMM -> O (bf16). tile 64i x 32n
// (n = mat*256+h merges t/u), K=512 in 16 chunks of 32, dbuf LDS. 512 thr,
// grid (16,16)=256. Per thread 2i x 2n. b1 folded. Pad-36 rows: reads free.
// ---------------------------------------------------------------------------
__global__ __launch_bounds__(512) void sp_gemm(
    const float* __restrict__ S, const float* __restrict__ W1,
    const float* __restrict__ b1, ushort* __restrict__ O) {
  __shared__ float Sl[2][64][36];   // 18.4 KB
  __shared__ float Wl[2][32][36];   //  9.2 KB

  const int tid = threadIdx.x;
  const int tx  = tid & 15;         // n = n0 + tx + 16b
  const int ty  = tid >> 4;         // i = i0 + 2ty + a, ty 0..31
  const int i0  = blockIdx.x * 64;
  const int n0  = blockIdx.y * 32;

  const int srow = tid >> 3;        // 0..63
  const int sc   = tid & 7;         // 0..7
  const int wn   = n0 + ((tid >> 3) & 31);
  const float* sp = S  + (size_t)(i0 + srow) * DD + 4 * sc;
  const float* wp = W1 + (size_t)(wn & 255) * (2 * DD) + (wn >> 8) * DD + 4 * sc;

  float4 sreg, wreg;
  auto ld = [&](int c) {
    sreg = *(const float4*)(sp + 32 * c);
    if (tid < 256) wreg = *(const float4*)(wp + 32 * c);
  };
  auto st = [&](int b) {
    *(float4*)&Sl[b][srow][4 * sc] = sreg;
    if (tid < 256) *(float4*)&Wl[b][tid >> 3][4 * sc] = wreg;
  };

  float acc[2][2] = {{0.f}};

  ld(0); st(0); __syncthreads();

  for (int c = 0; c < 16; ++c) {
    const int cur = c & 1;
    if (c < 15) ld(c + 1);
    #pragma unroll
    for (int k4 = 0; k4 < 8; ++k4) {
      const float4 wf0 = *(const float4*)&Wl[cur][tx][4 * k4];
      const float4 wf1 = *(const float4*)&Wl[cur][tx + 16][4 * k4];
      const float4 sf0 = *(const float4*)&Sl[cur][2 * ty][4 * k4];
      const float4 sf1 = *(const float4*)&Sl[cur][2 * ty + 1][4 * k4];
      acc[0][0] += sf0.x * wf0.x + sf0.y * wf0.y + sf0.z * wf0.z + sf0.w * wf0.w;
      acc[0][1] += sf0.x * wf1.x + sf0.y * wf1.y + sf0.z * wf1.z + sf0.w * wf1.w;
      acc[1][0] += sf1.x * wf0.x + sf1.y * wf0.y + sf1.z * wf0.z + sf1.w * wf0.w;
      acc[1][1] += sf1.x * wf1.x + sf1.y * wf1.y + sf1.z * wf1.z + sf1.w * wf1.w;
    }
    if (c < 15) st(cur ^ 1);
    __syncthreads();
  }

  #pragma unroll
  for (int b = 0; b < 2; ++b) {
    const int n = n0 + tx + 16 * b;
    const float bb = (n < 256) ? b1[n] : 0.f;
    ushort2 v;
    v.x = f2bf(acc[0][b] + bb);
    v.y = f2bf(acc[1][b] + bb);
    *(ushort2*)(O + (size_t)n * LL + i0 + 2 * ty) = v;
  }
}

// ---------------------------------------------------------------------------
// Kernel 2: pairwise, bf16 LDS panels. Block z covers h in [128z, 128z+128):
//   pz[z](i,j) = A_z(i) + B_z(j) + sum_hh |t_i+u_j| * w2_h  (relu=(x+|x|)/2,
// 0.25 in symsig). 256 thr, tile 64x64, 4i x 4j. Panels ushort[128][72] x2
// = 36.9 KB -> 4 blocks/CU = 16 waves/CU = 4 waves/SIMD, grid (16,16,2)=512.
// Inner: 2 ds_read_b64 per 16 cells (T 4-addr broadcast, U banks 0..31 once
// each -> conflict-free) + 8 unpack + 32 add/fma -> VALU-bound ~8.5us floor.
// ---------------------------------------------------------------------------
__global__ __launch_bounds__(256, 4) void sp_pairwise(
    const ushort* __restrict__ O, const float* __restrict__ W2,
    float* __restrict__ pz) {
  __shared__ ushort Tl[128][72];   // 18.4 KB
  __shared__ ushort Ul[128][72];   // 18.4 KB
  __shared__ float PR[2][128];
  __shared__ float As[64], Bs[64];

  const int tid = threadIdx.x;
  const int tx  = tid & 15;       // j = j0 + 4tx + b
  const int ty  = tid >> 4;       // i = i0 + 4ty + a, ty 0..15
  const int j0  = blockIdx.x * 64;
  const int i0  = blockIdx.y * 64;
  const int hz  = blockIdx.z * 128;

  // stage bf16 panels straight from O (8-B copies, coalesced 128-B segments)
  #pragma unroll
  for (int q = 0; q < 8; ++q) {
    const int m = q * 256 + tid;           // 0..2047
    const int hh = m >> 4;                 // 0..127
    const int g8 = (m & 15) * 4;           // ushort col
    *(ushort4*)&Tl[hh][g8] =
        *(const ushort4*)(O + (size_t)(hz + hh) * LL + i0 + g8);
    *(ushort4*)&Ul[hh][g8] =
        *(const ushort4*)(O + (size_t)(HH + hz + hh) * LL + j0 + g8);
  }
  __syncthreads();

  // rank-1 prologue over this h-half (bf16-consistent with the inner loop)
  {
    const int x = tid & 127, hs = tid >> 7;    // hs 0..1
    const ushort* pan = (x < 64) ? &Tl[0][x] : &Ul[0][x - 64];
    float p = 0.f;
    #pragma unroll 8
    for (int n = 0; n < 64; ++n) {
      const int hh = hs * 64 + n;
      const float v = __uint_as_float(((unsigned int)pan[hh * 72]) << 16);
      p = fmaf(v, W2[hz + hh], p);
    }
    PR[hs][x] = p;
  }
  __syncthreads();
  if (tid < 128) {
    const float s = PR[0][tid] + PR[1][tid];
    if (tid < 64) As[tid] = s; else Bs[tid - 64] = s;
  }
  __syncthreads();

  float acc[4][4] = {{0.f}};

  #pragma unroll 4
  for (int hh = 0; hh < 128; ++hh) {
    const uint2 tr = *(const uint2*)&Tl[hh][4 * ty];
    const uint2 ur = *(const uint2*)&Ul[hh][4 * tx];
    const float w = W2[hz + hh];
    const float tv[4] = {bf_lo(tr.x), bf_hi(tr.x), bf_lo(tr.y), bf_hi(tr.y)};
    const float uv[4] = {bf_lo(ur.x), bf_hi(ur.x), bf_lo(ur.y), bf_hi(ur.y)};
    #pragma unroll
    for (int a = 0; a < 4; ++a) {
      #pragma unroll
      for (int b = 0; b < 4; ++b) {
        acc[a][b] = fmaf(fabsf(tv[a] + uv[b]), w, acc[a][b]);
      }
    }
  }

  float* po = pz + (size_t)blockIdx.z * ((size_t)LL * LL);
  #pragma unroll
  for (int a = 0; a < 4; ++a) {
    const float Ai = As[4 * ty + a];
    float4 v;
    v.x = acc[a][0] + Ai + Bs[4 * tx + 0];
    v.y = acc[a][1] + Ai + Bs[4 * tx + 1];
    v.z = acc[a][2] + Ai + Bs[4 * tx + 2];
    v.w = acc[a][3] + Ai + Bs[4 * tx + 3];
    *(float4*)(po + (size_t)(i0 + 4 * ty + a) * LL + j0 + 4 * tx) = v;
  }
}

// ---------------------------------------------------------------------------
// Kernel 3 (R11-proven): out = sigmoid(0.25*(Q + Q^T) + b2), Q = pz0+pz1.
// 64x64 tiles, grid (16,16), 1024 thr, LDS transpose.
// ---------------------------------------------------------------------------
__global__ __launch_bounds__(1024) void sp_symsig(
    const float* __restrict__ pz, const float* __restrict__ b2,
    float* __restrict__ out) {
  __shared__ float B[64][65];
  const int i0 = blockIdx.y * 64;
  const int j0 = blockIdx.x * 64;
  const int r  = threadIdx.x >> 4;   // 0..63
  const int g  = threadIdx.x & 15;   // 0..15
  const size_t L2 = (size_t)LL * LL;

  const float* pm = pz + (size_t)(j0 + r) * LL + i0 + 4 * g;
  const float4 m0 = *(const float4*)(pm);
  const float4 m1 = *(const float4*)(pm + L2);
  B[r][4 * g + 0] = m0.x + m1.x;
  B[r][4 * g + 1] = m0.y + m1.y;
  B[r][4 * g + 2] = m0.z + m1.z;
  B[r][4 * g + 3] = m0.w + m1.w;
  __syncthreads();

  const float* pd = pz + (size_t)(i0 + r) * LL + j0 + 4 * g;
  const float4 d0 = *(const float4*)(pd);
  const float4 d1 = *(const float4*)(pd + L2);
  const float bb = b2[0];
  float4 o;
  float x;
  x = 0.25f * (d0.x + d1.x + B[4 * g + 0][r]) + bb; o.x = 1.f / (1.f + expf(-x));
  x = 0.25f * (d0.y + d1.y + B[4 * g + 1][r]) + bb; o.y = 1.f / (1.f + expf(-x));
  x = 0.25f * (d0.z + d1.z + B[4 * g + 2][r]) + bb; o.z = 1.f / (1.f + expf(-x));
  x = 0.25f * (d0.w + d1.w + B[4 * g + 3][r]) + bb; o.w = 1.f / (1.f + expf(-x));
  *(float4*)(out + (size_t)(i0 + r) * LL + j0 + 4 * g) = o;
}

// ---------------------------------------------------------------------------
extern "C" void kernel_launch(void* const* d_in, const int* in_sizes, int n_in,
                              void* d_out, int out_size, void* d_ws, size_t ws_size,
                              hipStream_t stream) {
  const float* S  = (const float*)d_in[0];   // [L, D]
  const float* W1 = (const float*)d_in[1];   // [H, 2D]
  const float* b1 = (const float*)d_in[2];   // [H]
  const float* W2 = (const float*)d_in[3];   // [1, H]
  const float* b2 = (const float*)d_in[4];   // [1]
  float* out = (float*)d_out;

  float* ws = (float*)d_ws;
  ushort* O = (ushort*)ws;                   // [512][1024] bf16 (1 MB)
  float* pz = ws + 262144;                   // [2][1024][1024] f32 (8 MB)

  hipLaunchKernelGGL(sp_gemm, dim3(16, 16), dim3(512), 0, stream,
                     S, W1, b1, O);
  hipLaunchKernelGGL(sp_pairwise, dim3(16, 16, 2), dim3(256), 0, stream,
                     O, W2, pz);
  hipLaunchKernelGGL(sp_symsig, dim3(16, 16), dim3(1024), 0, stream,
                     pz, b2, out);
}